// Round 1
// baseline (1856.129 us; speedup 1.0000x reference)
//
#include <hip/hip_runtime.h>
#include <hip/hip_bf16.h>
#include <cstdint>
#include <cstddef>

// Problem constants: N=32768, D=2048, H=4096, E=8, T = N/E = 4096.
#define NTOK 32768
#define DDIM 2048
#define HDIM 4096
#define NEXP 8
#define TTOK 4096

typedef __attribute__((ext_vector_type(8))) __bf16 bf16x8;
typedef __attribute__((ext_vector_type(4))) float f32x4;

#define MFMA_BF16(a, b, c) __builtin_amdgcn_mfma_f32_16x16x32_bf16((a), (b), (c), 0, 0, 0)

__device__ __forceinline__ unsigned short f2bf(float f) {
  unsigned int u = __builtin_bit_cast(unsigned int, f);
  u += 0x7FFFu + ((u >> 16) & 1u);   // round-to-nearest-even
  return (unsigned short)(u >> 16);
}

// ---------------- f32 -> bf16 convert (vectorized, grid-stride) ----------------
__global__ __launch_bounds__(256) void cvt_kernel(const float* __restrict__ src,
                                                  unsigned short* __restrict__ dst,
                                                  long n4) {
  long i = (long)blockIdx.x * blockDim.x + threadIdx.x;
  long stride = (long)gridDim.x * blockDim.x;
  const float4* s4 = (const float4*)src;
  ushort4* d4 = (ushort4*)dst;
  for (; i < n4; i += stride) {
    float4 v = s4[i];
    ushort4 o;
    o.x = f2bf(v.x); o.y = f2bf(v.y); o.z = f2bf(v.z); o.w = f2bf(v.w);
    d4[i] = o;
  }
}

// ------------- transpose w_down (E,H,D) f32 -> (E,D,H) bf16 -------------
__global__ __launch_bounds__(256) void transpose_wd(const float* __restrict__ w,
                                                    unsigned short* __restrict__ wt) {
  __shared__ unsigned short tile[64][66];  // +2 pad: column reads stride 33 banks
  const int e = blockIdx.z;
  const int h0 = blockIdx.y * 64;
  const int d0 = blockIdx.x * 64;
  const float* we = w + (size_t)e * HDIM * DDIM;
  unsigned short* wte = wt + (size_t)e * DDIM * HDIM;
  const int t = threadIdx.x;
  const int r = t >> 4;
  const int c4 = (t & 15) * 4;
#pragma unroll
  for (int p = 0; p < 4; ++p) {
    int h = r + p * 16;
    float4 v = *(const float4*)(we + (size_t)(h0 + h) * DDIM + d0 + c4);
    tile[h][c4 + 0] = f2bf(v.x);
    tile[h][c4 + 1] = f2bf(v.y);
    tile[h][c4 + 2] = f2bf(v.z);
    tile[h][c4 + 3] = f2bf(v.w);
  }
  __syncthreads();
#pragma unroll
  for (int p = 0; p < 4; ++p) {
    int d = r + p * 16;
    ushort4 o;
    o.x = tile[c4 + 0][d];
    o.y = tile[c4 + 1][d];
    o.z = tile[c4 + 2][d];
    o.w = tile[c4 + 3][d];
    *(ushort4*)(wte + (size_t)(d0 + d) * HDIM + h0 + c4) = o;
  }
}

// ------------- GEMM staging: 128 rows x 64 bf16, global_load_lds width=16 -------------
// LDS dest is linear (wave-uniform base + lane*16). Swizzle achieved by
// inverse-XOR on the GLOBAL source granule (rule #21): LDS granule (r,c)
// receives global granule (r, c ^ (r&7)); reads XOR the same way.
__device__ __forceinline__ void stage128x64(const unsigned short* __restrict__ g0,
                                            size_t stride_elems,
                                            unsigned short* lds, int tid) {
#pragma unroll
  for (int i = 0; i < 4; ++i) {
    int gi = i * 256 + tid;          // granule index 0..1023 (16B granules)
    int r = gi >> 3;                 // row 0..127
    int c = gi & 7;                  // granule-in-row 0..7 (64 bf16 = 8 granules)
    const unsigned short* src = g0 + (size_t)r * stride_elems + ((c ^ (r & 7)) << 3);
    __builtin_amdgcn_global_load_lds(
        (const __attribute__((address_space(1))) unsigned int*)src,
        (__attribute__((address_space(3))) unsigned int*)(lds + (size_t)gi * 8),
        16, 0, 0);
  }
}

__device__ __forceinline__ bf16x8 read_frag(const unsigned short* lds, int row, int cg) {
  return *(const bf16x8*)(lds + row * 64 + ((cg ^ (row & 7)) << 3));
}

// ------------- GEMM1 + SwiGLU: hidden = (x@Wu^T) * silu(x@Wg^T), bf16 out -------------
// A: x_bf16 (E*T, D); B: wug_bf16 (E, 2H, D) rows [h0,h0+128) and [H+h0,...)
__global__ __launch_bounds__(256, 2) void gemm1_swiglu(
    const unsigned short* __restrict__ Xb,
    const unsigned short* __restrict__ Wb,
    unsigned short* __restrict__ Hid) {
  __shared__ unsigned short sA[128 * 64];
  __shared__ unsigned short sBu[128 * 64];
  __shared__ unsigned short sBg[128 * 64];
  const int e = blockIdx.z;
  const int bm = blockIdx.y;   // token tile 0..31
  const int bn = blockIdx.x;   // h tile 0..31
  const unsigned short* Xe = Xb + (size_t)e * TTOK * DDIM + (size_t)bm * 128 * DDIM;
  const unsigned short* Wu = Wb + (size_t)e * 2 * HDIM * DDIM + (size_t)bn * 128 * DDIM;
  const unsigned short* Wg = Wu + (size_t)HDIM * DDIM;
  const int tid = threadIdx.x;
  const int lane = tid & 63;
  const int wid = tid >> 6;
  const int wm = (wid & 1) * 64;
  const int wn = (wid >> 1) * 64;
  const int lr = lane & 15;
  const int lk = lane >> 4;

  f32x4 au[4][4], ag[4][4];
#pragma unroll
  for (int i = 0; i < 4; ++i)
#pragma unroll
    for (int j = 0; j < 4; ++j) {
      au[i][j] = f32x4{0.f, 0.f, 0.f, 0.f};
      ag[i][j] = f32x4{0.f, 0.f, 0.f, 0.f};
    }

  for (int kt = 0; kt < DDIM / 64; ++kt) {
    if (kt) __syncthreads();
    stage128x64(Xe + kt * 64, DDIM, sA, tid);
    stage128x64(Wu + kt * 64, DDIM, sBu, tid);
    stage128x64(Wg + kt * 64, DDIM, sBg, tid);
    __syncthreads();
#pragma unroll
    for (int kh = 0; kh < 2; ++kh) {
      const int cg = kh * 4 + lk;
      bf16x8 a[4], bu[4], bg[4];
#pragma unroll
      for (int mi = 0; mi < 4; ++mi) a[mi] = read_frag(sA, wm + mi * 16 + lr, cg);
#pragma unroll
      for (int ni = 0; ni < 4; ++ni) bu[ni] = read_frag(sBu, wn + ni * 16 + lr, cg);
#pragma unroll
      for (int ni = 0; ni < 4; ++ni) bg[ni] = read_frag(sBg, wn + ni * 16 + lr, cg);
#pragma unroll
      for (int mi = 0; mi < 4; ++mi)
#pragma unroll
        for (int ni = 0; ni < 4; ++ni) {
          au[mi][ni] = MFMA_BF16(a[mi], bu[ni], au[mi][ni]);
          ag[mi][ni] = MFMA_BF16(a[mi], bg[ni], ag[mi][ni]);
        }
    }
  }

  // epilogue: hidden = up * silu(gate); C layout col=lane&15, row=(lane>>4)*4+reg
  unsigned short* He = Hid + (size_t)e * TTOK * HDIM + (size_t)(bm * 128) * HDIM + bn * 128;
#pragma unroll
  for (int mi = 0; mi < 4; ++mi)
#pragma unroll
    for (int ni = 0; ni < 4; ++ni)
#pragma unroll
      for (int r = 0; r < 4; ++r) {
        int row = wm + mi * 16 + lk * 4 + r;
        int col = wn + ni * 16 + lr;
        float up = au[mi][ni][r];
        float g = ag[mi][ni][r];
        float hid = up * g / (1.f + __expf(-g));
        He[(size_t)row * HDIM + col] = f2bf(hid);
      }
}

// ------------- GEMM2: out = hidden @ w_down  (f32 out) -------------
// A: hidden (E,T,H) bf16; B: wdT (E,D,H) bf16 (K = H contiguous for both)
__global__ __launch_bounds__(256, 2) void gemm2_down(
    const unsigned short* __restrict__ Hid,
    const unsigned short* __restrict__ WdT,
    float* __restrict__ Out) {
  __shared__ unsigned short sA[128 * 64];
  __shared__ unsigned short sB[128 * 64];
  const int e = blockIdx.z;
  const int bm = blockIdx.y;   // token tile 0..31
  const int bn = blockIdx.x;   // d tile 0..15
  const unsigned short* Ae = Hid + (size_t)e * TTOK * HDIM + (size_t)bm * 128 * HDIM;
  const unsigned short* Be = WdT + (size_t)e * DDIM * HDIM + (size_t)bn * 128 * HDIM;
  const int tid = threadIdx.x;
  const int lane = tid & 63;
  const int wid = tid >> 6;
  const int wm = (wid & 1) * 64;
  const int wn = (wid >> 1) * 64;
  const int lr = lane & 15;
  const int lk = lane >> 4;

  f32x4 acc[4][4];
#pragma unroll
  for (int i = 0; i < 4; ++i)
#pragma unroll
    for (int j = 0; j < 4; ++j) acc[i][j] = f32x4{0.f, 0.f, 0.f, 0.f};

  for (int kt = 0; kt < HDIM / 64; ++kt) {
    if (kt) __syncthreads();
    stage128x64(Ae + kt * 64, HDIM, sA, tid);
    stage128x64(Be + kt * 64, HDIM, sB, tid);
    __syncthreads();
#pragma unroll
    for (int kh = 0; kh < 2; ++kh) {
      const int cg = kh * 4 + lk;
      bf16x8 a[4], b[4];
#pragma unroll
      for (int mi = 0; mi < 4; ++mi) a[mi] = read_frag(sA, wm + mi * 16 + lr, cg);
#pragma unroll
      for (int ni = 0; ni < 4; ++ni) b[ni] = read_frag(sB, wn + ni * 16 + lr, cg);
#pragma unroll
      for (int mi = 0; mi < 4; ++mi)
#pragma unroll
        for (int ni = 0; ni < 4; ++ni)
          acc[mi][ni] = MFMA_BF16(a[mi], b[ni], acc[mi][ni]);
    }
  }

  float* Oe = Out + ((size_t)e * TTOK + bm * 128) * DDIM + bn * 128;
#pragma unroll
  for (int mi = 0; mi < 4; ++mi)
#pragma unroll
    for (int ni = 0; ni < 4; ++ni)
#pragma unroll
      for (int r = 0; r < 4; ++r) {
        int row = wm + mi * 16 + lk * 4 + r;
        int col = wn + ni * 16 + lr;
        Oe[(size_t)row * DDIM + col] = acc[mi][ni][r];
      }
}

extern "C" void kernel_launch(void* const* d_in, const int* in_sizes, int n_in,
                              void* d_out, int out_size, void* d_ws, size_t ws_size,
                              hipStream_t stream) {
  const float* x = (const float*)d_in[0];
  const float* wug = (const float*)d_in[1];
  const float* wd = (const float*)d_in[2];
  // d_in[3] = batch_size_per_expert: uniform N/E per the reference's reshape; unused.
  float* out = (float*)d_out;

  // Workspace layout (bf16 elements). Total = 768 MiB.
  unsigned short* xb   = (unsigned short*)d_ws;                    // 32768*2048
  unsigned short* wugb = xb   + (size_t)NTOK * DDIM;               // 8*8192*2048
  unsigned short* wdT  = wugb + (size_t)NEXP * 2 * HDIM * DDIM;    // 8*2048*4096
  unsigned short* hid  = wdT  + (size_t)NEXP * DDIM * HDIM;        // 8*4096*4096

  cvt_kernel<<<4096, 256, 0, stream>>>(x, xb, (long)NTOK * DDIM / 4);
  cvt_kernel<<<4096, 256, 0, stream>>>(wug, wugb, (long)NEXP * 2 * HDIM * DDIM / 4);
  transpose_wd<<<dim3(DDIM / 64, HDIM / 64, NEXP), 256, 0, stream>>>(wd, wdT);
  gemm1_swiglu<<<dim3(HDIM / 128, TTOK / 128, NEXP), 256, 0, stream>>>(xb, wugb, hid);
  gemm2_down<<<dim3(DDIM / 128, TTOK / 128, NEXP), 256, 0, stream>>>(hid, wdT, out);
}